// Round 1
// baseline (523.692 us; speedup 1.0000x reference)
//
#include <hip/hip_runtime.h>
#include <hip/hip_bf16.h>

// Sizes fixed by the problem
#define B  2048
#define D  4096
#define D3 12288   // 3*D
#define L  3

struct Ptrs8 { const float* p[8]; };

// ---------------------------------------------------------------------------
// K1: column means of the 8 [B, D] inputs — partial sums over row chunks.
// grid: (colchunk=4, rowchunk=16, matrix=8), block 256. Each thread owns 4
// columns (float4) and sums 128 rows. partials layout: [m][rc][D].
// ---------------------------------------------------------------------------
__global__ void k_mean_partial(Ptrs8 in, float* __restrict__ partials) {
    const int cc = blockIdx.x, rc = blockIdx.y, m = blockIdx.z;
    const float* __restrict__ src = in.p[m];
    const int col0 = cc * 1024 + threadIdx.x * 4;
    const int row0 = rc * 128;
    float4 acc = {0.f, 0.f, 0.f, 0.f};
    for (int r = 0; r < 128; ++r) {
        const float4 v = *reinterpret_cast<const float4*>(
            src + (size_t)(row0 + r) * D + col0);
        acc.x += v.x; acc.y += v.y; acc.z += v.z; acc.w += v.w;
    }
    *reinterpret_cast<float4*>(partials + ((size_t)(m * 16 + rc)) * D + col0) = acc;
}

// ---------------------------------------------------------------------------
// K1b: finalize means, init h (rows 0-3 = shared pre_means, rows 4-7 = per
// stream now_means), and s_vec = sum of shared rows. 16 blocks x 256.
// ---------------------------------------------------------------------------
__global__ void k_mean_finalize(const float* __restrict__ partials,
                                float* __restrict__ means,
                                float* __restrict__ h,
                                float* __restrict__ svec) {
    const int d = blockIdx.x * 256 + threadIdx.x;
    float mv[8];
    #pragma unroll
    for (int m = 0; m < 8; ++m) {
        float s = 0.f;
        #pragma unroll
        for (int rc = 0; rc < 16; ++rc) s += partials[(size_t)(m * 16 + rc) * D + d];
        mv[m] = s * (1.0f / (float)B);
        means[m * D + d] = mv[m];
    }
    float ssum = 0.f;
    #pragma unroll
    for (int j = 0; j < 4; ++j) {          // shared rows = pre means (inputs 4..7)
        h[j * D + d] = mv[4 + j];
        ssum += mv[4 + j];
    }
    #pragma unroll
    for (int s = 0; s < 4; ++s)            // stream rows = now means (inputs 0..3)
        h[(4 + s) * D + d] = mv[s];
    svec[d] = ssum;
}

// ---------------------------------------------------------------------------
// K3: aggmsg partial: aggmsg[d'] = sum_d svec[d] * W[d][d'].
// grid (colchunk=4, rowchunk=64), block 256; partials [64][D].
// ---------------------------------------------------------------------------
__global__ void k_aggmsg_partial(const float* __restrict__ Wl,
                                 const float* __restrict__ svec,
                                 float* __restrict__ partials) {
    const int col0 = blockIdx.x * 1024 + threadIdx.x * 4;
    const int row0 = blockIdx.y * 64;
    float4 acc = {0.f, 0.f, 0.f, 0.f};
    for (int r = 0; r < 64; ++r) {
        const float sv = svec[row0 + r];
        const float4 w = *reinterpret_cast<const float4*>(
            Wl + (size_t)(row0 + r) * D + col0);
        acc.x += sv * w.x; acc.y += sv * w.y; acc.z += sv * w.z; acc.w += sv * w.w;
    }
    *reinterpret_cast<float4*>(partials + (size_t)blockIdx.y * D + col0) = acc;
}

__global__ void k_aggmsg_reduce(const float* __restrict__ partials,
                                float* __restrict__ aggmsg) {
    const int d = blockIdx.x * 256 + threadIdx.x;
    float s = 0.f;
    #pragma unroll
    for (int r = 0; r < 64; ++r) s += partials[(size_t)r * D + d];
    aggmsg[d] = s;
}

// ---------------------------------------------------------------------------
// K4: gi0[k] = dot(w_ih[k,:], aggmsg) + b_ih[k].  One wave handles 4 rows.
// 12288 rows -> 3072 waves -> 768 blocks of 256.
// ---------------------------------------------------------------------------
__global__ void k_gi0(const float* __restrict__ w_ih,
                      const float* __restrict__ aggmsg,
                      const float* __restrict__ b_ih,
                      float* __restrict__ gi0) {
    const int wid  = (blockIdx.x * blockDim.x + threadIdx.x) >> 6;
    const int lane = threadIdx.x & 63;
    const int k0 = wid * 4;
    float acc[4] = {0.f, 0.f, 0.f, 0.f};
    for (int i = 0; i < 16; ++i) {
        const int idx = i * 256 + lane * 4;
        const float4 a = *reinterpret_cast<const float4*>(aggmsg + idx);
        #pragma unroll
        for (int r = 0; r < 4; ++r) {
            const float4 w = *reinterpret_cast<const float4*>(
                w_ih + (size_t)(k0 + r) * D + idx);
            acc[r] += w.x * a.x + w.y * a.y + w.z * a.z + w.w * a.w;
        }
    }
    #pragma unroll
    for (int r = 0; r < 4; ++r) {
        float v = acc[r];
        #pragma unroll
        for (int off = 32; off; off >>= 1) v += __shfl_xor(v, off);
        if (lane == 0) gi0[k0 + r] = v + b_ih[k0 + r];
    }
}

// ---------------------------------------------------------------------------
// K5: gh[j][k] = dot(w_hh[k,:], h_j) + b_hh[k], j = 0..7 (batched over the 8
// state rows). One wave handles 4 w_hh rows so the small h vectors are read
// from L2 only ~3072 times total. gh layout: [8][D3].
// ---------------------------------------------------------------------------
__global__ void k_gh(const float* __restrict__ w_hh,
                     const float* __restrict__ h,
                     const float* __restrict__ b_hh,
                     float* __restrict__ gh) {
    const int wid  = (blockIdx.x * blockDim.x + threadIdx.x) >> 6;
    const int lane = threadIdx.x & 63;
    const int k0 = wid * 4;
    float acc[4][8] = {};
    for (int i = 0; i < 16; ++i) {
        const int idx = i * 256 + lane * 4;
        float4 hv[8];
        #pragma unroll
        for (int j = 0; j < 8; ++j)
            hv[j] = *reinterpret_cast<const float4*>(h + j * D + idx);
        #pragma unroll
        for (int r = 0; r < 4; ++r) {
            const float4 w = *reinterpret_cast<const float4*>(
                w_hh + (size_t)(k0 + r) * D + idx);
            #pragma unroll
            for (int j = 0; j < 8; ++j)
                acc[r][j] += w.x * hv[j].x + w.y * hv[j].y
                           + w.z * hv[j].z + w.w * hv[j].w;
        }
    }
    #pragma unroll
    for (int r = 0; r < 4; ++r) {
        #pragma unroll
        for (int j = 0; j < 8; ++j) {
            float v = acc[r][j];
            #pragma unroll
            for (int off = 32; off; off >>= 1) v += __shfl_xor(v, off);
            if (lane == 0) gh[(size_t)j * D3 + k0 + r] = v + b_hh[k0 + r];
        }
    }
}

// ---------------------------------------------------------------------------
// K6: GRU pointwise update for all 8 rows; rows 0-3 (shared) use gi = b_ih
// (agg = 0), rows 4-7 (streams) use gi0. Also emits s_vec for next layer.
// 16 blocks x 256.
// ---------------------------------------------------------------------------
__device__ __forceinline__ float sigmoidf_(float x) {
    return 1.0f / (1.0f + __expf(-x));
}

__global__ void k_gru(const float* __restrict__ gi0,
                      const float* __restrict__ gh,
                      const float* __restrict__ b_ih,
                      float* __restrict__ h,
                      float* __restrict__ svec) {
    const int d = blockIdx.x * 256 + threadIdx.x;
    const float bir = b_ih[d], biz = b_ih[D + d], bin = b_ih[2 * D + d];
    const float gir = gi0[d],  giz = gi0[D + d],  gin = gi0[2 * D + d];
    float ssum = 0.f;
    #pragma unroll
    for (int j = 0; j < 8; ++j) {
        const float ir = (j < 4) ? bir : gir;
        const float iz = (j < 4) ? biz : giz;
        const float in = (j < 4) ? bin : gin;
        const float hr = gh[(size_t)j * D3 + d];
        const float hz = gh[(size_t)j * D3 + D + d];
        const float hn = gh[(size_t)j * D3 + 2 * D + d];
        const float hv = h[j * D + d];
        const float r = sigmoidf_(ir + hr);
        const float z = sigmoidf_(iz + hz);
        const float n = tanhf(in + r * hn);
        const float hnew = (1.f - z) * n + z * hv;
        h[j * D + d] = hnew;
        if (j < 4) ssum += hnew;
    }
    svec[d] = ssum;
}

// ---------------------------------------------------------------------------
// K7: loss = 10 * sum_s mean_d (h0_s - pre_mean_s)^2. Single block.
// ---------------------------------------------------------------------------
__global__ void k_loss(const float* __restrict__ h,
                       const float* __restrict__ means,
                       float* __restrict__ out) {
    __shared__ float red[4];
    float acc = 0.f;
    for (int idx = threadIdx.x; idx < 4 * D; idx += 256) {
        const int s = idx >> 12;
        const int d = idx & (D - 1);
        const float diff = h[(4 + s) * D + d] - means[(4 + s) * D + d];
        acc += diff * diff;
    }
    #pragma unroll
    for (int off = 32; off; off >>= 1) acc += __shfl_xor(acc, off);
    const int wave = threadIdx.x >> 6, lane = threadIdx.x & 63;
    if (lane == 0) red[wave] = acc;
    __syncthreads();
    if (threadIdx.x == 0)
        out[0] = (red[0] + red[1] + red[2] + red[3]) * (10.0f / (float)D);
}

// ---------------------------------------------------------------------------
extern "C" void kernel_launch(void* const* d_in, const int* in_sizes, int n_in,
                              void* d_out, int out_size, void* d_ws, size_t ws_size,
                              hipStream_t stream) {
    const float* W    = (const float*)d_in[8];
    const float* w_ih = (const float*)d_in[9];
    const float* w_hh = (const float*)d_in[10];
    const float* b_ih = (const float*)d_in[11];
    const float* b_hh = (const float*)d_in[12];

    float* ws     = (float*)d_ws;
    float* mpart  = ws;                    // 8*16*D   = 524288
    float* means  = mpart  + 8 * 16 * D;   // 8*D      =  32768
    float* h      = means  + 8 * D;        // 8*D      =  32768
    float* svec   = h      + 8 * D;        // D        =   4096
    float* apart  = svec   + D;            // 64*D     = 262144
    float* aggmsg = apart  + 64 * D;       // D        =   4096
    float* gi0    = aggmsg + D;            // D3       =  12288
    float* gh     = gi0    + D3;           // 8*D3     =  98304

    Ptrs8 in8;
    for (int i = 0; i < 8; ++i) in8.p[i] = (const float*)d_in[i];

    k_mean_partial<<<dim3(4, 16, 8), 256, 0, stream>>>(in8, mpart);
    k_mean_finalize<<<16, 256, 0, stream>>>(mpart, means, h, svec);

    for (int l = 0; l < L; ++l) {
        const float* Wl = W + (size_t)l * D * D;
        k_aggmsg_partial<<<dim3(4, 64), 256, 0, stream>>>(Wl, svec, apart);
        k_aggmsg_reduce<<<16, 256, 0, stream>>>(apart, aggmsg);
        k_gh <<<768, 256, 0, stream>>>(w_hh, h, b_hh, gh);
        k_gi0<<<768, 256, 0, stream>>>(w_ih, aggmsg, b_ih, gi0);
        k_gru<<<16, 256, 0, stream>>>(gi0, gh, b_ih, h, svec);
    }

    k_loss<<<1, 256, 0, stream>>>(h, means, (float*)d_out);
}

// Round 2
// 446.927 us; speedup vs baseline: 1.1718x; 1.1718x over previous
//
#include <hip/hip_runtime.h>
#include <hip/hip_bf16.h>

// Sizes fixed by the problem
#define B  2048
#define D  4096
#define D3 12288   // 3*D
#define L  3

struct Ptrs8 { const float* p[8]; };

__device__ __forceinline__ unsigned short f2bf(float f) {
    union { float f; unsigned int u; } v; v.f = f;
    unsigned int r = v.u + 0x7FFFu + ((v.u >> 16) & 1u);  // round-nearest-even
    return (unsigned short)(r >> 16);
}
__device__ __forceinline__ float bfbits_lo(unsigned int u) {
    union { unsigned int u; float f; } v; v.u = u << 16; return v.f;
}
__device__ __forceinline__ float bfbits_hi(unsigned int u) {
    union { unsigned int u; float f; } v; v.u = u & 0xFFFF0000u; return v.f;
}

// ---------------------------------------------------------------------------
// K1: column means of the 8 [B, D] inputs — partial sums over row chunks.
// ---------------------------------------------------------------------------
__global__ void k_mean_partial(Ptrs8 in, float* __restrict__ partials) {
    const int cc = blockIdx.x, rc = blockIdx.y, m = blockIdx.z;
    const float* __restrict__ src = in.p[m];
    const int col0 = cc * 1024 + threadIdx.x * 4;
    const int row0 = rc * 128;
    float4 acc = {0.f, 0.f, 0.f, 0.f};
    for (int r = 0; r < 128; ++r) {
        const float4 v = *reinterpret_cast<const float4*>(
            src + (size_t)(row0 + r) * D + col0);
        acc.x += v.x; acc.y += v.y; acc.z += v.z; acc.w += v.w;
    }
    *reinterpret_cast<float4*>(partials + ((size_t)(m * 16 + rc)) * D + col0) = acc;
}

__global__ void k_mean_finalize(const float* __restrict__ partials,
                                float* __restrict__ means,
                                float* __restrict__ h,
                                float* __restrict__ svec) {
    const int d = blockIdx.x * 256 + threadIdx.x;
    float mv[8];
    #pragma unroll
    for (int m = 0; m < 8; ++m) {
        float s = 0.f;
        #pragma unroll
        for (int rc = 0; rc < 16; ++rc) s += partials[(size_t)(m * 16 + rc) * D + d];
        mv[m] = s * (1.0f / (float)B);
        means[m * D + d] = mv[m];
    }
    float ssum = 0.f;
    #pragma unroll
    for (int j = 0; j < 4; ++j) {          // shared rows = pre means (inputs 4..7)
        h[j * D + d] = mv[4 + j];
        ssum += mv[4 + j];
    }
    #pragma unroll
    for (int s = 0; s < 4; ++s)            // stream rows = now means (inputs 0..3)
        h[(4 + s) * D + d] = mv[s];
    svec[d] = ssum;
}

// ---------------------------------------------------------------------------
// K3: aggmsg[d'] = sum_d svec[d] * W[d][d']  (partial over row chunks)
// ---------------------------------------------------------------------------
__global__ void k_aggmsg_partial(const float* __restrict__ Wl,
                                 const float* __restrict__ svec,
                                 float* __restrict__ partials) {
    const int col0 = blockIdx.x * 1024 + threadIdx.x * 4;
    const int row0 = blockIdx.y * 64;
    float4 acc = {0.f, 0.f, 0.f, 0.f};
    for (int r = 0; r < 64; ++r) {
        const float sv = svec[row0 + r];
        const float4 w = *reinterpret_cast<const float4*>(
            Wl + (size_t)(row0 + r) * D + col0);
        acc.x += sv * w.x; acc.y += sv * w.y; acc.z += sv * w.z; acc.w += sv * w.w;
    }
    *reinterpret_cast<float4*>(partials + (size_t)blockIdx.y * D + col0) = acc;
}

__global__ void k_aggmsg_reduce(const float* __restrict__ partials,
                                float* __restrict__ aggmsg) {
    const int d = blockIdx.x * 256 + threadIdx.x;
    float s = 0.f;
    #pragma unroll
    for (int r = 0; r < 64; ++r) s += partials[(size_t)r * D + d];
    aggmsg[d] = s;
}

// ---------------------------------------------------------------------------
// K4 (layer 0): fused gates. Waves 0..3071 compute gh[j][k]=w_hh[k,:]·h_j
// (j=0..7, 4 rows/wave); waves 3072..6143 compute gi0[k]=w_ih[k,:]·aggmsg.
// Both read fp32 weights from HBM and emit a bf16-rn copy for layers 1-2
// (201 MB, fits the 256 MB LLC).
// ---------------------------------------------------------------------------
__global__ void k_gates_f32(const float* __restrict__ w_ih,
                            const float* __restrict__ w_hh,
                            const float* __restrict__ h,
                            const float* __restrict__ aggmsg,
                            const float* __restrict__ b_ih,
                            const float* __restrict__ b_hh,
                            float* __restrict__ gi0,
                            float* __restrict__ gh,
                            unsigned short* __restrict__ wih_bf,
                            unsigned short* __restrict__ whh_bf) {
    const int gwid = (blockIdx.x * blockDim.x + threadIdx.x) >> 6;
    const int lane = threadIdx.x & 63;
    if (gwid < 3072) {
        const int k0 = gwid * 4;
        float acc[4][8] = {};
        for (int i = 0; i < 16; ++i) {
            const int idx = i * 256 + lane * 4;
            float4 hv[8];
            #pragma unroll
            for (int j = 0; j < 8; ++j)
                hv[j] = *reinterpret_cast<const float4*>(h + j * D + idx);
            #pragma unroll
            for (int r = 0; r < 4; ++r) {
                const size_t off = (size_t)(k0 + r) * D + idx;
                const float4 w = *reinterpret_cast<const float4*>(w_hh + off);
                ushort4 wb;
                wb.x = f2bf(w.x); wb.y = f2bf(w.y); wb.z = f2bf(w.z); wb.w = f2bf(w.w);
                *reinterpret_cast<ushort4*>(whh_bf + off) = wb;
                #pragma unroll
                for (int j = 0; j < 8; ++j)
                    acc[r][j] += w.x * hv[j].x + w.y * hv[j].y
                               + w.z * hv[j].z + w.w * hv[j].w;
            }
        }
        #pragma unroll
        for (int r = 0; r < 4; ++r) {
            #pragma unroll
            for (int j = 0; j < 8; ++j) {
                float v = acc[r][j];
                #pragma unroll
                for (int off = 32; off; off >>= 1) v += __shfl_xor(v, off);
                if (lane == 0) gh[(size_t)j * D3 + k0 + r] = v + b_hh[k0 + r];
            }
        }
    } else {
        const int k0 = (gwid - 3072) * 4;
        float acc[4] = {0.f, 0.f, 0.f, 0.f};
        for (int i = 0; i < 16; ++i) {
            const int idx = i * 256 + lane * 4;
            const float4 a = *reinterpret_cast<const float4*>(aggmsg + idx);
            #pragma unroll
            for (int r = 0; r < 4; ++r) {
                const size_t off = (size_t)(k0 + r) * D + idx;
                const float4 w = *reinterpret_cast<const float4*>(w_ih + off);
                ushort4 wb;
                wb.x = f2bf(w.x); wb.y = f2bf(w.y); wb.z = f2bf(w.z); wb.w = f2bf(w.w);
                *reinterpret_cast<ushort4*>(wih_bf + off) = wb;
                acc[r] += w.x * a.x + w.y * a.y + w.z * a.z + w.w * a.w;
            }
        }
        #pragma unroll
        for (int r = 0; r < 4; ++r) {
            float v = acc[r];
            #pragma unroll
            for (int off = 32; off; off >>= 1) v += __shfl_xor(v, off);
            if (lane == 0) gi0[k0 + r] = v + b_ih[k0 + r];
        }
    }
}

// ---------------------------------------------------------------------------
// K4b (layers 1-2): same fused gates, reading the bf16 weight copies
// (mostly LLC-resident). 8 bf16/lane per uint4 load.
// ---------------------------------------------------------------------------
__global__ void k_gates_bf(const unsigned short* __restrict__ wih_bf,
                           const unsigned short* __restrict__ whh_bf,
                           const float* __restrict__ h,
                           const float* __restrict__ aggmsg,
                           const float* __restrict__ b_ih,
                           const float* __restrict__ b_hh,
                           float* __restrict__ gi0,
                           float* __restrict__ gh) {
    const int gwid = (blockIdx.x * blockDim.x + threadIdx.x) >> 6;
    const int lane = threadIdx.x & 63;
    if (gwid < 3072) {
        const int k0 = gwid * 4;
        float acc[4][8] = {};
        for (int i = 0; i < 8; ++i) {
            const int idx = i * 512 + lane * 8;
            float4 hv[8][2];
            #pragma unroll
            for (int j = 0; j < 8; ++j) {
                hv[j][0] = *reinterpret_cast<const float4*>(h + j * D + idx);
                hv[j][1] = *reinterpret_cast<const float4*>(h + j * D + idx + 4);
            }
            #pragma unroll
            for (int r = 0; r < 4; ++r) {
                const uint4 wu = *reinterpret_cast<const uint4*>(
                    whh_bf + (size_t)(k0 + r) * D + idx);
                float wf[8];
                wf[0] = bfbits_lo(wu.x); wf[1] = bfbits_hi(wu.x);
                wf[2] = bfbits_lo(wu.y); wf[3] = bfbits_hi(wu.y);
                wf[4] = bfbits_lo(wu.z); wf[5] = bfbits_hi(wu.z);
                wf[6] = bfbits_lo(wu.w); wf[7] = bfbits_hi(wu.w);
                #pragma unroll
                for (int j = 0; j < 8; ++j)
                    acc[r][j] += wf[0] * hv[j][0].x + wf[1] * hv[j][0].y
                               + wf[2] * hv[j][0].z + wf[3] * hv[j][0].w
                               + wf[4] * hv[j][1].x + wf[5] * hv[j][1].y
                               + wf[6] * hv[j][1].z + wf[7] * hv[j][1].w;
            }
        }
        #pragma unroll
        for (int r = 0; r < 4; ++r) {
            #pragma unroll
            for (int j = 0; j < 8; ++j) {
                float v = acc[r][j];
                #pragma unroll
                for (int off = 32; off; off >>= 1) v += __shfl_xor(v, off);
                if (lane == 0) gh[(size_t)j * D3 + k0 + r] = v + b_hh[k0 + r];
            }
        }
    } else {
        const int k0 = (gwid - 3072) * 4;
        float acc[4] = {0.f, 0.f, 0.f, 0.f};
        for (int i = 0; i < 8; ++i) {
            const int idx = i * 512 + lane * 8;
            const float4 a0 = *reinterpret_cast<const float4*>(aggmsg + idx);
            const float4 a1 = *reinterpret_cast<const float4*>(aggmsg + idx + 4);
            #pragma unroll
            for (int r = 0; r < 4; ++r) {
                const uint4 wu = *reinterpret_cast<const uint4*>(
                    wih_bf + (size_t)(k0 + r) * D + idx);
                acc[r] += bfbits_lo(wu.x) * a0.x + bfbits_hi(wu.x) * a0.y
                        + bfbits_lo(wu.y) * a0.z + bfbits_hi(wu.y) * a0.w
                        + bfbits_lo(wu.z) * a1.x + bfbits_hi(wu.z) * a1.y
                        + bfbits_lo(wu.w) * a1.z + bfbits_hi(wu.w) * a1.w;
            }
        }
        #pragma unroll
        for (int r = 0; r < 4; ++r) {
            float v = acc[r];
            #pragma unroll
            for (int off = 32; off; off >>= 1) v += __shfl_xor(v, off);
            if (lane == 0) gi0[k0 + r] = v + b_ih[k0 + r];
        }
    }
}

// ---------------------------------------------------------------------------
// K6: GRU pointwise update; rows 0-3 (shared) use gi = b_ih (agg = 0).
// ---------------------------------------------------------------------------
__device__ __forceinline__ float sigmoidf_(float x) {
    return 1.0f / (1.0f + __expf(-x));
}

__global__ void k_gru(const float* __restrict__ gi0,
                      const float* __restrict__ gh,
                      const float* __restrict__ b_ih,
                      float* __restrict__ h,
                      float* __restrict__ svec) {
    const int d = blockIdx.x * 256 + threadIdx.x;
    const float bir = b_ih[d], biz = b_ih[D + d], bin = b_ih[2 * D + d];
    const float gir = gi0[d],  giz = gi0[D + d],  gin = gi0[2 * D + d];
    float ssum = 0.f;
    #pragma unroll
    for (int j = 0; j < 8; ++j) {
        const float ir = (j < 4) ? bir : gir;
        const float iz = (j < 4) ? biz : giz;
        const float in = (j < 4) ? bin : gin;
        const float hr = gh[(size_t)j * D3 + d];
        const float hz = gh[(size_t)j * D3 + D + d];
        const float hn = gh[(size_t)j * D3 + 2 * D + d];
        const float hv = h[j * D + d];
        const float r = sigmoidf_(ir + hr);
        const float z = sigmoidf_(iz + hz);
        const float n = tanhf(in + r * hn);
        const float hnew = (1.f - z) * n + z * hv;
        h[j * D + d] = hnew;
        if (j < 4) ssum += hnew;
    }
    svec[d] = ssum;
}

// ---------------------------------------------------------------------------
// K7: loss = 10 * sum_s mean_d (h0_s - pre_mean_s)^2.
// ---------------------------------------------------------------------------
__global__ void k_loss(const float* __restrict__ h,
                       const float* __restrict__ means,
                       float* __restrict__ out) {
    __shared__ float red[4];
    float acc = 0.f;
    for (int idx = threadIdx.x; idx < 4 * D; idx += 256) {
        const int s = idx >> 12;
        const int d = idx & (D - 1);
        const float diff = h[(4 + s) * D + d] - means[(4 + s) * D + d];
        acc += diff * diff;
    }
    #pragma unroll
    for (int off = 32; off; off >>= 1) acc += __shfl_xor(acc, off);
    const int wave = threadIdx.x >> 6, lane = threadIdx.x & 63;
    if (lane == 0) red[wave] = acc;
    __syncthreads();
    if (threadIdx.x == 0)
        out[0] = (red[0] + red[1] + red[2] + red[3]) * (10.0f / (float)D);
}

// ---------------------------------------------------------------------------
extern "C" void kernel_launch(void* const* d_in, const int* in_sizes, int n_in,
                              void* d_out, int out_size, void* d_ws, size_t ws_size,
                              hipStream_t stream) {
    const float* W    = (const float*)d_in[8];
    const float* w_ih = (const float*)d_in[9];
    const float* w_hh = (const float*)d_in[10];
    const float* b_ih = (const float*)d_in[11];
    const float* b_hh = (const float*)d_in[12];

    float* ws     = (float*)d_ws;
    float* mpart  = ws;                    // 8*16*D   = 524288 f
    float* means  = mpart  + 8 * 16 * D;   // 8*D
    float* h      = means  + 8 * D;        // 8*D
    float* svec   = h      + 8 * D;        // D
    float* apart  = svec   + D;            // 64*D
    float* aggmsg = apart  + 64 * D;       // D
    float* gi0    = aggmsg + D;            // D3
    float* gh     = gi0    + D3;           // 8*D3
    float* wbase  = gh     + 8 * D3;
    unsigned short* wih_bf = (unsigned short*)wbase;            // D3*D bf16 = 96 MB
    unsigned short* whh_bf = wih_bf + (size_t)D3 * D;           // D3*D bf16 = 96 MB

    Ptrs8 in8;
    for (int i = 0; i < 8; ++i) in8.p[i] = (const float*)d_in[i];

    k_mean_partial<<<dim3(4, 16, 8), 256, 0, stream>>>(in8, mpart);
    k_mean_finalize<<<16, 256, 0, stream>>>(mpart, means, h, svec);

    for (int l = 0; l < L; ++l) {
        const float* Wl = W + (size_t)l * D * D;
        k_aggmsg_partial<<<dim3(4, 64), 256, 0, stream>>>(Wl, svec, apart);
        k_aggmsg_reduce<<<16, 256, 0, stream>>>(apart, aggmsg);
        if (l == 0)
            k_gates_f32<<<1536, 256, 0, stream>>>(w_ih, w_hh, h, aggmsg,
                                                  b_ih, b_hh, gi0, gh,
                                                  wih_bf, whh_bf);
        else
            k_gates_bf<<<1536, 256, 0, stream>>>(wih_bf, whh_bf, h, aggmsg,
                                                 b_ih, b_hh, gi0, gh);
        k_gru<<<16, 256, 0, stream>>>(gi0, gh, b_ih, h, svec);
    }

    k_loss<<<1, 256, 0, stream>>>(h, means, (float*)d_out);
}

// Round 3
// 390.320 us; speedup vs baseline: 1.3417x; 1.1450x over previous
//
#include <hip/hip_runtime.h>
#include <hip/hip_bf16.h>

// Sizes fixed by the problem
#define B  2048
#define D  4096
#define D3 12288   // 3*D
#define L  3

struct Ptrs8 { const float* p[8]; };

// ext_vector types (HIP float4 is a struct; __builtin_nontemporal_load needs
// real vector types)
typedef float        f32x4 __attribute__((ext_vector_type(4)));
typedef unsigned int u32x2 __attribute__((ext_vector_type(2)));
typedef unsigned short u16x4 __attribute__((ext_vector_type(4)));

__device__ __forceinline__ f32x4 ldnt4(const float* p) {
    return __builtin_nontemporal_load(reinterpret_cast<const f32x4*>(p));
}
__device__ __forceinline__ f32x4 ld4(const float* p) {
    return *reinterpret_cast<const f32x4*>(p);
}

__device__ __forceinline__ unsigned short f2bf(float f) {
    union { float f; unsigned int u; } v; v.f = f;
    unsigned int r = v.u + 0x7FFFu + ((v.u >> 16) & 1u);  // round-nearest-even
    return (unsigned short)(r >> 16);
}
__device__ __forceinline__ float bf_lo(unsigned int u) {
    union { unsigned int u; float f; } v; v.u = u << 16; return v.f;
}
__device__ __forceinline__ float bf_hi(unsigned int u) {
    union { unsigned int u; float f; } v; v.u = u & 0xFFFF0000u; return v.f;
}

// ---------------------------------------------------------------------------
// K1: column means of the 8 [B, D] inputs — partial sums over row chunks.
// NT loads: inputs are streamed exactly once; keep them out of the LLC.
// ---------------------------------------------------------------------------
__global__ void k_mean_partial(Ptrs8 in, float* __restrict__ partials) {
    const int cc = blockIdx.x, rc = blockIdx.y, m = blockIdx.z;
    const float* __restrict__ src = in.p[m];
    const int col0 = cc * 1024 + threadIdx.x * 4;
    const int row0 = rc * 128;
    f32x4 acc = {0.f, 0.f, 0.f, 0.f};
    for (int r = 0; r < 128; ++r) {
        const f32x4 v = ldnt4(src + (size_t)(row0 + r) * D + col0);
        acc += v;
    }
    *reinterpret_cast<f32x4*>(partials + ((size_t)(m * 16 + rc)) * D + col0) = acc;
}

__global__ void k_mean_finalize(const float* __restrict__ partials,
                                float* __restrict__ means,
                                float* __restrict__ h,
                                float* __restrict__ svec) {
    const int d = blockIdx.x * 256 + threadIdx.x;
    float mv[8];
    #pragma unroll
    for (int m = 0; m < 8; ++m) {
        float s = 0.f;
        #pragma unroll
        for (int rc = 0; rc < 16; ++rc) s += partials[(size_t)(m * 16 + rc) * D + d];
        mv[m] = s * (1.0f / (float)B);
        means[m * D + d] = mv[m];
    }
    float ssum = 0.f;
    #pragma unroll
    for (int j = 0; j < 4; ++j) {          // shared rows = pre means (inputs 4..7)
        h[j * D + d] = mv[4 + j];
        ssum += mv[4 + j];
    }
    #pragma unroll
    for (int s = 0; s < 4; ++s)            // stream rows = now means (inputs 0..3)
        h[(4 + s) * D + d] = mv[s];
    svec[d] = ssum;
}

// ---------------------------------------------------------------------------
// K3: aggmsg[d'] = sum_d svec[d] * W[d][d']  (partial over row chunks).
// NT loads on W (streamed once per layer; protect LLC).
// ---------------------------------------------------------------------------
__global__ void k_aggmsg_partial(const float* __restrict__ Wl,
                                 const float* __restrict__ svec,
                                 float* __restrict__ partials) {
    const int col0 = blockIdx.x * 1024 + threadIdx.x * 4;
    const int row0 = blockIdx.y * 64;
    f32x4 acc = {0.f, 0.f, 0.f, 0.f};
    for (int r = 0; r < 64; ++r) {
        const float sv = svec[row0 + r];
        const f32x4 w = ldnt4(Wl + (size_t)(row0 + r) * D + col0);
        acc += sv * w;
    }
    *reinterpret_cast<f32x4*>(partials + (size_t)blockIdx.y * D + col0) = acc;
}

__global__ void k_aggmsg_reduce(const float* __restrict__ partials,
                                float* __restrict__ aggmsg) {
    const int d = blockIdx.x * 256 + threadIdx.x;
    float s = 0.f;
    #pragma unroll
    for (int r = 0; r < 64; ++r) s += partials[(size_t)r * D + d];
    aggmsg[d] = s;
}

// ---------------------------------------------------------------------------
// K4 (layer 0): fused gates. Waves 0..3071: gh[j][k] = w_hh[k,:]·h_j (4 rows
// per wave, all 8 j). Waves 3072..6143: gi0[k] = w_ih[k,:]·aggmsg. fp32
// weights NT-loaded (read once); bf16 copy stored temporal (wanted in LLC).
// __launch_bounds__(256,4): 128-VGPR budget — live set ~95, no spills.
// ---------------------------------------------------------------------------
__global__ __launch_bounds__(256, 4)
void k_gates_f32(const float* __restrict__ w_ih,
                 const float* __restrict__ w_hh,
                 const float* __restrict__ h,
                 const float* __restrict__ aggmsg,
                 const float* __restrict__ b_ih,
                 const float* __restrict__ b_hh,
                 float* __restrict__ gi0,
                 float* __restrict__ gh,
                 unsigned short* __restrict__ wih_bf,
                 unsigned short* __restrict__ whh_bf) {
    const int gwid = (blockIdx.x * blockDim.x + threadIdx.x) >> 6;
    const int lane = threadIdx.x & 63;
    if (gwid < 3072) {
        const int k0 = gwid * 4;
        float acc[4][8] = {};
        for (int i = 0; i < 16; ++i) {
            const int idx = i * 256 + lane * 4;
            f32x4 w[4];
            #pragma unroll
            for (int r = 0; r < 4; ++r)
                w[r] = ldnt4(w_hh + (size_t)(k0 + r) * D + idx);
            #pragma unroll
            for (int r = 0; r < 4; ++r) {
                u16x4 wb;
                wb.x = f2bf(w[r].x); wb.y = f2bf(w[r].y);
                wb.z = f2bf(w[r].z); wb.w = f2bf(w[r].w);
                *reinterpret_cast<u16x4*>(whh_bf + (size_t)(k0 + r) * D + idx) = wb;
            }
            f32x4 hv[8];
            #pragma unroll
            for (int j = 0; j < 8; ++j) hv[j] = ld4(h + j * D + idx);
            #pragma unroll
            for (int r = 0; r < 4; ++r)
                #pragma unroll
                for (int j = 0; j < 8; ++j)
                    acc[r][j] += w[r].x * hv[j].x + w[r].y * hv[j].y
                               + w[r].z * hv[j].z + w[r].w * hv[j].w;
        }
        #pragma unroll
        for (int r = 0; r < 4; ++r)
            #pragma unroll
            for (int j = 0; j < 8; ++j) {
                float v = acc[r][j];
                #pragma unroll
                for (int off = 32; off; off >>= 1) v += __shfl_xor(v, off);
                if (lane == 0) gh[(size_t)j * D3 + k0 + r] = v + b_hh[k0 + r];
            }
    } else {
        const int k0 = (gwid - 3072) * 4;
        float acc[4] = {0.f, 0.f, 0.f, 0.f};
        for (int i = 0; i < 16; ++i) {
            const int idx = i * 256 + lane * 4;
            const f32x4 a = ld4(aggmsg + idx);
            #pragma unroll
            for (int r = 0; r < 4; ++r) {
                const f32x4 w = ldnt4(w_ih + (size_t)(k0 + r) * D + idx);
                u16x4 wb;
                wb.x = f2bf(w.x); wb.y = f2bf(w.y);
                wb.z = f2bf(w.z); wb.w = f2bf(w.w);
                *reinterpret_cast<u16x4*>(wih_bf + (size_t)(k0 + r) * D + idx) = wb;
                acc[r] += w.x * a.x + w.y * a.y + w.z * a.z + w.w * a.w;
            }
        }
        #pragma unroll
        for (int r = 0; r < 4; ++r) {
            float v = acc[r];
            #pragma unroll
            for (int off = 32; off; off >>= 1) v += __shfl_xor(v, off);
            if (lane == 0) gi0[k0 + r] = v + b_ih[k0 + r];
        }
    }
}

// ---------------------------------------------------------------------------
// K4b (layers 1-2): gates from the bf16 copies (LLC-resident). 4 bf16/row/step
// via uint2; hv[8] hoisted. Live ≈ 103 regs ≤ 128 budget.
// ---------------------------------------------------------------------------
__global__ __launch_bounds__(256, 4)
void k_gates_bf(const unsigned short* __restrict__ wih_bf,
                const unsigned short* __restrict__ whh_bf,
                const float* __restrict__ h,
                const float* __restrict__ aggmsg,
                const float* __restrict__ b_ih,
                const float* __restrict__ b_hh,
                float* __restrict__ gi0,
                float* __restrict__ gh) {
    const int gwid = (blockIdx.x * blockDim.x + threadIdx.x) >> 6;
    const int lane = threadIdx.x & 63;
    if (gwid < 3072) {
        const int k0 = gwid * 4;
        float acc[4][8] = {};
        for (int i = 0; i < 16; ++i) {
            const int idx = i * 256 + lane * 4;
            u32x2 wu[4];
            #pragma unroll
            for (int r = 0; r < 4; ++r)
                wu[r] = *reinterpret_cast<const u32x2*>(
                    whh_bf + (size_t)(k0 + r) * D + idx);
            f32x4 hv[8];
            #pragma unroll
            for (int j = 0; j < 8; ++j) hv[j] = ld4(h + j * D + idx);
            #pragma unroll
            for (int r = 0; r < 4; ++r) {
                const float w0 = bf_lo(wu[r].x), w1 = bf_hi(wu[r].x);
                const float w2 = bf_lo(wu[r].y), w3 = bf_hi(wu[r].y);
                #pragma unroll
                for (int j = 0; j < 8; ++j)
                    acc[r][j] += w0 * hv[j].x + w1 * hv[j].y
                               + w2 * hv[j].z + w3 * hv[j].w;
            }
        }
        #pragma unroll
        for (int r = 0; r < 4; ++r)
            #pragma unroll
            for (int j = 0; j < 8; ++j) {
                float v = acc[r][j];
                #pragma unroll
                for (int off = 32; off; off >>= 1) v += __shfl_xor(v, off);
                if (lane == 0) gh[(size_t)j * D3 + k0 + r] = v + b_hh[k0 + r];
            }
    } else {
        const int k0 = (gwid - 3072) * 4;
        float acc[4] = {0.f, 0.f, 0.f, 0.f};
        for (int i = 0; i < 16; ++i) {
            const int idx = i * 256 + lane * 4;
            const f32x4 a = ld4(aggmsg + idx);
            #pragma unroll
            for (int r = 0; r < 4; ++r) {
                const u32x2 wu = *reinterpret_cast<const u32x2*>(
                    wih_bf + (size_t)(k0 + r) * D + idx);
                acc[r] += bf_lo(wu.x) * a.x + bf_hi(wu.x) * a.y
                        + bf_lo(wu.y) * a.z + bf_hi(wu.y) * a.w;
            }
        }
        #pragma unroll
        for (int r = 0; r < 4; ++r) {
            float v = acc[r];
            #pragma unroll
            for (int off = 32; off; off >>= 1) v += __shfl_xor(v, off);
            if (lane == 0) gi0[k0 + r] = v + b_ih[k0 + r];
        }
    }
}

// ---------------------------------------------------------------------------
// K6: GRU pointwise update; rows 0-3 (shared) use gi = b_ih (agg = 0).
// ---------------------------------------------------------------------------
__device__ __forceinline__ float sigmoidf_(float x) {
    return 1.0f / (1.0f + __expf(-x));
}

__global__ void k_gru(const float* __restrict__ gi0,
                      const float* __restrict__ gh,
                      const float* __restrict__ b_ih,
                      float* __restrict__ h,
                      float* __restrict__ svec) {
    const int d = blockIdx.x * 256 + threadIdx.x;
    const float bir = b_ih[d], biz = b_ih[D + d], bin = b_ih[2 * D + d];
    const float gir = gi0[d],  giz = gi0[D + d],  gin = gi0[2 * D + d];
    float ssum = 0.f;
    #pragma unroll
    for (int j = 0; j < 8; ++j) {
        const float ir = (j < 4) ? bir : gir;
        const float iz = (j < 4) ? biz : giz;
        const float in = (j < 4) ? bin : gin;
        const float hr = gh[(size_t)j * D3 + d];
        const float hz = gh[(size_t)j * D3 + D + d];
        const float hn = gh[(size_t)j * D3 + 2 * D + d];
        const float hv = h[j * D + d];
        const float r = sigmoidf_(ir + hr);
        const float z = sigmoidf_(iz + hz);
        const float n = tanhf(in + r * hn);
        const float hnew = (1.f - z) * n + z * hv;
        h[j * D + d] = hnew;
        if (j < 4) ssum += hnew;
    }
    svec[d] = ssum;
}

// ---------------------------------------------------------------------------
// K7: loss = 10 * sum_s mean_d (h0_s - pre_mean_s)^2.
// ---------------------------------------------------------------------------
__global__ void k_loss(const float* __restrict__ h,
                       const float* __restrict__ means,
                       float* __restrict__ out) {
    __shared__ float red[4];
    float acc = 0.f;
    for (int idx = threadIdx.x; idx < 4 * D; idx += 256) {
        const int s = idx >> 12;
        const int d = idx & (D - 1);
        const float diff = h[(4 + s) * D + d] - means[(4 + s) * D + d];
        acc += diff * diff;
    }
    #pragma unroll
    for (int off = 32; off; off >>= 1) acc += __shfl_xor(acc, off);
    const int wave = threadIdx.x >> 6, lane = threadIdx.x & 63;
    if (lane == 0) red[wave] = acc;
    __syncthreads();
    if (threadIdx.x == 0)
        out[0] = (red[0] + red[1] + red[2] + red[3]) * (10.0f / (float)D);
}

// ---------------------------------------------------------------------------
extern "C" void kernel_launch(void* const* d_in, const int* in_sizes, int n_in,
                              void* d_out, int out_size, void* d_ws, size_t ws_size,
                              hipStream_t stream) {
    const float* W    = (const float*)d_in[8];
    const float* w_ih = (const float*)d_in[9];
    const float* w_hh = (const float*)d_in[10];
    const float* b_ih = (const float*)d_in[11];
    const float* b_hh = (const float*)d_in[12];

    float* ws     = (float*)d_ws;
    float* mpart  = ws;                    // 8*16*D
    float* means  = mpart  + 8 * 16 * D;   // 8*D
    float* h      = means  + 8 * D;        // 8*D
    float* svec   = h      + 8 * D;        // D
    float* apart  = svec   + D;            // 64*D
    float* aggmsg = apart  + 64 * D;       // D
    float* gi0    = aggmsg + D;            // D3
    float* gh     = gi0    + D3;           // 8*D3
    float* wbase  = gh     + 8 * D3;
    unsigned short* wih_bf = (unsigned short*)wbase;   // D3*D bf16 = 96 MB
    unsigned short* whh_bf = wih_bf + (size_t)D3 * D;  // D3*D bf16 = 96 MB

    Ptrs8 in8;
    for (int i = 0; i < 8; ++i) in8.p[i] = (const float*)d_in[i];

    k_mean_partial<<<dim3(4, 16, 8), 256, 0, stream>>>(in8, mpart);
    k_mean_finalize<<<16, 256, 0, stream>>>(mpart, means, h, svec);

    for (int l = 0; l < L; ++l) {
        const float* Wl = W + (size_t)l * D * D;
        k_aggmsg_partial<<<dim3(4, 64), 256, 0, stream>>>(Wl, svec, apart);
        k_aggmsg_reduce<<<16, 256, 0, stream>>>(apart, aggmsg);
        if (l == 0)
            k_gates_f32<<<1536, 256, 0, stream>>>(w_ih, w_hh, h, aggmsg,
                                                  b_ih, b_hh, gi0, gh,
                                                  wih_bf, whh_bf);
        else
            k_gates_bf<<<1536, 256, 0, stream>>>(wih_bf, whh_bf, h, aggmsg,
                                                 b_ih, b_hh, gi0, gh);
        k_gru<<<16, 256, 0, stream>>>(gi0, gh, b_ih, h, svec);
    }

    k_loss<<<1, 256, 0, stream>>>(h, means, (float*)d_out);
}